// Round 8
// baseline (1307.926 us; speedup 1.0000x reference)
//
#include <hip/hip_runtime.h>
#include <stdint.h>
#include <stddef.h>
#include <math.h>

// WindowAttention MI355X (gfx950). B=16 C=512 H=W=64 WS=16 HEADS=8 d=64.
// L=256 windows, N=256 positions, attention batches (n,h)=2048 of 256x256,d=64.
//
// R4: SPILL fix. R2/R3 both ran at VGPR_Count=64 (launch_bounds(512,4) caps
//     the allocator at 128; acc[4][4]+frags+addrs > 128 -> accumulators spilled
//     to scratch). Scratch VMEM traffic was the FETCH/WRITE amplification
//     (WRITE 811MB vs 201MB unique; MfmaUtil 6.3% = pure stall).
//  - per-wave tile 64 rows x 32 couts: acc[4][2]=32 VGPR, demand ~85 << 128.
//    8 waves x 32 couts = 256/pass, 6 passes -> block weight traffic unchanged.
//  - epilogue: per-wave [16][36]-stride transpose buffer (writes 2-way free,
//    reads row-distinct) -> 16 full 64B-line stores per instruction.
//  - gemm_out same split (2 passes). attn_win untouched ((512,2) = no spill).
//
// Workspace: q[n][h][l][d] 67MB (o overwrites in-place) | k 67MB | v 67MB |
//            w1p bf16 1.5MB | w2p bf16 0.5MB.  Total ~203 MB.

typedef __bf16 bf16;
typedef __attribute__((ext_vector_type(8))) __bf16 bf16x8;
typedef __attribute__((ext_vector_type(4))) __bf16 bf16x4;
typedef __attribute__((ext_vector_type(4))) float f32x4;

#define MFMA16(A, B, C) __builtin_amdgcn_mfma_f32_16x16x32_bf16((A), (B), (C), 0, 0, 0)

__device__ __forceinline__ float fast_exp2(float x) { return __builtin_amdgcn_exp2f(x); }

// XOR-swizzled A-tile element index: rows x 512 cols bf16, unpadded.
// granule (16B) index = (c>>3) ^ (n>>4 & 7) ^ (n & 7): spreads both the
// n-strided staging writes and the b128 frag reads.
__device__ __forceinline__ int aswz(int n, int c) {
  int g = (c >> 3) ^ ((n >> 4) & 7) ^ (n & 7);
  return n * 512 + (g << 3) + (c & 7);
}

// ---------------------------------------------------------------- cvt + pack
// Pack weights into per-wave fragment order:
//   wp[((t*16 + ks)*64 + lane)*8 + e] = wf[t*16 + (lane&15)][ks*32 + (lane>>4)*8 + e]
// so a wave's (tile t, kslice ks) load is one contiguous 1KB block.
// w1: 96 tiles (1536 couts), w2: 32 tiles (512 couts). 1 thread per (t,ks,lane).
__global__ void cvt_pack(const float* __restrict__ w1f, const float* __restrict__ w2f,
                         bf16* __restrict__ w1p, bf16* __restrict__ w2p) {
  int i = blockIdx.x * 256 + threadIdx.x;   // 0..131071
  const float* src;
  bf16* dst;
  if (i < 98304) { src = w1f; dst = w1p; }
  else           { src = w2f; dst = w2p; i -= 98304; }
  int lane = i & 63;
  int ks   = (i >> 6) & 15;
  int t    = i >> 10;
  int cout = t * 16 + (lane & 15);
  int c0   = ks * 32 + (lane >> 4) * 8;
  float4 a = *(const float4*)(src + (size_t)cout * 512 + c0);
  float4 b = *(const float4*)(src + (size_t)cout * 512 + c0 + 4);
  bf16x8 r;
  r[0] = (bf16)a.x; r[1] = (bf16)a.y; r[2] = (bf16)a.z; r[3] = (bf16)a.w;
  r[4] = (bf16)b.x; r[5] = (bf16)b.y; r[6] = (bf16)b.z; r[7] = (bf16)b.w;
  *(bf16x8*)(dst + (size_t)i * 8) = r;
}

// ---------------------------------------------------------------- QKV GEMM
// Block = 64 rows (window l, n-quarter) x K=512, A swizzled in 64KB LDS.
// 8 waves x 32 couts; 6 passes of 256 couts; dst/head/d-half from t0w.
// Per wave per ks: 2 packed 1KB weight loads (1-deep prefetch) + 4 ds_read_b128
// + 8 MFMA. acc[4][2]=32 VGPR -> no spill at the 128-cap (16 waves/CU).
__global__ void __launch_bounds__(512, 4) gemm_qkv(
    const float* __restrict__ x, const bf16* __restrict__ w1p,
    const float* __restrict__ b1,
    bf16* __restrict__ qo, bf16* __restrict__ ko, bf16* __restrict__ vo) {
  extern __shared__ bf16 Al[];              // 64*512 swizzled + epilogue buf
  bf16* Ep = Al + 64 * 512;                 // 8 waves x [16][36]
  const int tid = threadIdx.x;
  const int bm  = blockIdx.x;               // 0..1023
  const int l   = bm >> 2;
  const int n0  = (bm & 3) << 6;
  const int b   = l >> 4, ih = (l >> 2) & 3, iw = l & 3;
  const int h0  = ih * 16 + (n0 >> 4);      // 4 h-rows of the window
  const int w0  = iw * 16;

  // stage A: 64 n-rows x 512 c, fp32 gather -> bf16 swizzled LDS
  for (int j = 0; j < 16; ++j) {
    int f4  = j * 512 + tid;                // 0..8191
    int c   = f4 >> 4;                      // 16 float4 per channel
    int qq  = f4 & 15;
    int wsh = qq >> 2;                      // 0..3
    int w4  = (qq & 3) << 2;
    float4 xf = *(const float4*)(x + (((b * 512 + c) * 64 + h0 + wsh) * 64 + w0 + w4));
    int nb = wsh * 16 + w4;                 // 0..60
    Al[aswz(nb + 0, c)] = (bf16)xf.x;
    Al[aswz(nb + 1, c)] = (bf16)xf.y;
    Al[aswz(nb + 2, c)] = (bf16)xf.z;
    Al[aswz(nb + 3, c)] = (bf16)xf.w;
  }
  __syncthreads();

  const int wave = tid >> 6, lane = tid & 63;
  const int l15 = lane & 15, quad = lane >> 4;
  bf16* Epw = Ep + wave * 16 * 36;
  const f32x4 fz = {0.f, 0.f, 0.f, 0.f};

  for (int nc = 0; nc < 6; ++nc) {
    const int t0w = nc * 256 + wave * 32;   // cout base (32-aligned)
    const int tb  = t0w >> 4;               // base 16-cout tile (2 tiles)
    f32x4 acc[4][2];
#pragma unroll
    for (int a = 0; a < 4; ++a)
#pragma unroll
      for (int c2 = 0; c2 < 2; ++c2) acc[a][c2] = fz;

    bf16x8 bfr[2];
#pragma unroll
    for (int ct = 0; ct < 2; ++ct)
      bfr[ct] = *(const bf16x8*)&w1p[((size_t)((tb + ct) * 16 + 0) * 64 + lane) * 8];
#pragma unroll
    for (int ks = 0; ks < 16; ++ks) {
      bf16x8 bnx[2];
      if (ks < 15) {
#pragma unroll
        for (int ct = 0; ct < 2; ++ct)
          bnx[ct] = *(const bf16x8*)&w1p[((size_t)((tb + ct) * 16 + ks + 1) * 64 + lane) * 8];
      }
      bf16x8 af[4];
#pragma unroll
      for (int lt = 0; lt < 4; ++lt)
        af[lt] = *(const bf16x8*)&Al[aswz(lt * 16 + l15, ks * 32 + quad * 8)];
#pragma unroll
      for (int lt = 0; lt < 4; ++lt)
#pragma unroll
        for (int ct = 0; ct < 2; ++ct)
          acc[lt][ct] = MFMA16(af[lt], bfr[ct], acc[lt][ct]);
#pragma unroll
      for (int ct = 0; ct < 2; ++ct) bfr[ct] = bnx[ct];
    }

    // epilogue: per-wave [16][36] transpose -> 16 x 64B full-line stores/instr
    const int which = t0w >> 9;
    bf16* dst = (which == 0) ? qo : (which == 1) ? ko : vo;
    const float scale = (which == 0) ? 0.125f : 1.0f;
    const int hh = (t0w & 511) >> 6;        // head
    const int dh = (t0w >> 5) & 1;          // d-half (0..31 / 32..63)
    float bias[2];
#pragma unroll
    for (int ct = 0; ct < 2; ++ct) bias[ct] = b1[t0w + ct * 16 + l15];

    const int rrow = lane >> 2, c4 = lane & 3;
#pragma unroll
    for (int lt = 0; lt < 4; ++lt) {
#pragma unroll
      for (int ct = 0; ct < 2; ++ct)
#pragma unroll
        for (int r = 0; r < 4; ++r)
          Epw[(quad * 4 + r) * 36 + ct * 16 + l15] =
              (bf16)((acc[lt][ct][r] + bias[ct]) * scale);
      bf16x8 vv = *(const bf16x8*)&Epw[rrow * 36 + c4 * 8];
      int n = n0 + lt * 16 + rrow;
      *(bf16x8*)&dst[((size_t)(n * 8 + hh) * 256 + l) * 64 + dh * 32 + c4 * 8] = vv;
    }
  }
}

// ---------------------------------------------------------------- attention
// One block per (n,h). K LDS [256][72], V^T LDS [64][264], per-wave P [16][264].
// Output overwrites q in-place; writes via per-wave transpose -> 128B chunks.
__global__ void __launch_bounds__(512, 2) attn_win(
    bf16* __restrict__ qio, const bf16* __restrict__ kg, const bf16* __restrict__ vg) {
  extern __shared__ bf16 sm[];
  bf16* Kl = sm;
  bf16* Vt = sm + 256 * 72;
  bf16* Pl = Vt + 64 * 264;
  const int tid = threadIdx.x;
  const int bb = blockIdx.x;
  const int n = bb >> 3, h = bb & 7;
  const size_t base = (size_t)(n * 8 + h) * 16384;
  const bf16* Kg = kg + base;
  const bf16* Vg = vg + base;
  bf16* Qg = qio + base;

  for (int j = 0; j < 4; ++j) {
    int cc = j * 512 + tid;
    int m = cc >> 3, dc = cc & 7;
    bf16x8 t = *(const bf16x8*)(Kg + m * 64 + dc * 8);
    *(bf16x8*)&Kl[m * 72 + dc * 8] = t;
  }
  for (int j = 0; j < 4; ++j) {
    int cc = j * 512 + tid;
    int dc = cc >> 8, m = cc & 255;
    bf16x8 t = *(const bf16x8*)(Vg + m * 64 + dc * 8);
#pragma unroll
    for (int s = 0; s < 8; ++s) Vt[(dc * 8 + s) * 264 + m] = t[s];
  }

  const int wave = tid >> 6, lane = tid & 63;
  const int l15 = lane & 15, quad = lane >> 4;
  const int lb = wave * 32;
  bf16* Pw = Pl + wave * 16 * 264;

  bf16x8 qf[2][2];
#pragma unroll
  for (int lt = 0; lt < 2; ++lt)
#pragma unroll
    for (int ks = 0; ks < 2; ++ks)
      qf[lt][ks] = *(const bf16x8*)(Qg + (lb + lt * 16 + l15) * 64 + ks * 32 + quad * 8);

  __syncthreads();

  const f32x4 fz = {0.f, 0.f, 0.f, 0.f};
  const float LOG2E = 1.44269504088896340736f;
  for (int lt = 0; lt < 2; ++lt) {
    f32x4 s[16];
#pragma unroll
    for (int mt = 0; mt < 16; ++mt) s[mt] = fz;
#pragma unroll
    for (int mt = 0; mt < 16; ++mt)
#pragma unroll
      for (int ks = 0; ks < 2; ++ks) {
        bf16x8 kf = *(const bf16x8*)&Kl[(mt * 16 + l15) * 72 + ks * 32 + quad * 8];
        s[mt] = MFMA16(qf[lt][ks], kf, s[mt]);
      }
    float rmax[4], rsum[4];
#pragma unroll
    for (int r = 0; r < 4; ++r) {
      float mx = s[0][r];
#pragma unroll
      for (int mt = 1; mt < 16; ++mt) mx = fmaxf(mx, s[mt][r]);
#pragma unroll
      for (int xo = 1; xo < 16; xo <<= 1) mx = fmaxf(mx, __shfl_xor(mx, xo, 16));
      rmax[r] = mx;
      rsum[r] = 0.f;
    }
#pragma unroll
    for (int mt = 0; mt < 16; ++mt) {
#pragma unroll
      for (int r = 0; r < 4; ++r) {
        float p = fast_exp2((s[mt][r] - rmax[r]) * LOG2E);
        bf16 pb = (bf16)p;
        rsum[r] += (float)pb;
        Pw[(quad * 4 + r) * 264 + mt * 16 + l15] = pb;
      }
    }
#pragma unroll
    for (int r = 0; r < 4; ++r)
#pragma unroll
      for (int xo = 1; xo < 16; xo <<= 1) rsum[r] += __shfl_xor(rsum[r], xo, 16);

    bf16x8 pf[8];
#pragma unroll
    for (int mk = 0; mk < 8; ++mk)
      pf[mk] = *(const bf16x8*)&Pw[l15 * 264 + mk * 32 + quad * 8];
    f32x4 of[4];
#pragma unroll
    for (int dt = 0; dt < 4; ++dt) of[dt] = fz;
#pragma unroll
    for (int dt = 0; dt < 4; ++dt)
#pragma unroll
      for (int mk = 0; mk < 8; ++mk) {
        bf16x8 vf = *(const bf16x8*)&Vt[(dt * 16 + l15) * 264 + mk * 32 + quad * 8];
        of[dt] = MFMA16(pf[mk], vf, of[dt]);
      }
    float inv[4];
#pragma unroll
    for (int r = 0; r < 4; ++r) inv[r] = 1.0f / rsum[r];

    // o-write: per-wave transpose (reuse Pw) -> 128B contiguous bf16x8 stores
    bf16* Ew = Pw;  // [16][72] region
#pragma unroll
    for (int dt = 0; dt < 4; ++dt)
#pragma unroll
      for (int r = 0; r < 4; ++r)
        Ew[(quad * 4 + r) * 72 + dt * 16 + l15] = (bf16)(of[dt][r] * inv[r]);
    const int rr = lane >> 3, ch8 = (lane & 7) * 8;
#pragma unroll
    for (int half = 0; half < 2; ++half) {
      int row = half * 8 + rr;
      bf16x8 vv = *(const bf16x8*)&Ew[row * 72 + ch8];
      *(bf16x8*)(Qg + (lb + lt * 16 + row) * 64 + ch8) = vv;
    }
  }
}

// ---------------------------------------------------------------- out proj
// Swapped MFMA operands: D = W2 x O^T, C-layout row=cout col=n, so stores are
// full 64B fp32 lines along w. 8 waves x 32 couts, 2 passes. acc[4][2]=32 VGPR.
__global__ void __launch_bounds__(512, 4) gemm_out(
    const bf16* __restrict__ og, const bf16* __restrict__ w2p,
    const float* __restrict__ b2, float* __restrict__ out) {
  extern __shared__ bf16 Al[];  // 64*512 swizzled
  const int tid = threadIdx.x;
  const int bm = blockIdx.x;    // 0..1023
  const int l = bm >> 2;
  const int n0 = (bm & 3) << 6;
  const int b = l >> 4, ih = (l >> 2) & 3, iw = l & 3;

  for (int j = 0; j < 8; ++j) {  // o[n][h][l][d] gather -> swizzled LDS rows
    int cc = j * 512 + tid;      // 0..4095
    int nl = cc >> 6;            // 0..63
    int ch = cc & 63;
    int hh = ch >> 3, d8 = (ch & 7) * 8;
    bf16x8 t = *(const bf16x8*)(og + ((size_t)((n0 + nl) * 8 + hh) * 256 + l) * 64 + d8);
    *(bf16x8*)&Al[aswz(nl, ch * 8)] = t;
  }
  __syncthreads();

  const int wave = tid >> 6, lane = tid & 63;
  const int l15 = lane & 15, quad = lane >> 4;
  const f32x4 fz = {0.f, 0.f, 0.f, 0.f};

  for (int nc = 0; nc < 2; ++nc) {
    const int t0w = nc * 256 + wave * 32;   // this wave's 32 couts
    const int tb  = t0w >> 4;
    f32x4 acc[4][2];
#pragma unroll
    for (int a = 0; a < 4; ++a)
#pragma unroll
      for (int c2 = 0; c2 < 2; ++c2) acc[a][c2] = fz;

    bf16x8 bfr[2];
#pragma unroll
    for (int ct = 0; ct < 2; ++ct)
      bfr[ct] = *(const bf16x8*)&w2p[((size_t)((tb + ct) * 16 + 0) * 64 + lane) * 8];
#pragma unroll
    for (int ks = 0; ks < 16; ++ks) {
      bf16x8 bnx[2];
      if (ks < 15) {
#pragma unroll
        for (int ct = 0; ct < 2; ++ct)
          bnx[ct] = *(const bf16x8*)&w2p[((size_t)((tb + ct) * 16 + ks + 1) * 64 + lane) * 8];
      }
      bf16x8 af[4];
#pragma unroll
      for (int lt = 0; lt < 4; ++lt)
        af[lt] = *(const bf16x8*)&Al[aswz(lt * 16 + l15, ks * 32 + quad * 8)];
#pragma unroll
      for (int lt = 0; lt < 4; ++lt)
#pragma unroll
        for (int ct = 0; ct < 2; ++ct)
          acc[lt][ct] = MFMA16(bfr[ct], af[lt], acc[lt][ct]);  // swapped: rows=cout
#pragma unroll
      for (int ct = 0; ct < 2; ++ct) bfr[ct] = bnx[ct];
    }

#pragma unroll
    for (int ct = 0; ct < 2; ++ct) {
      float4 bias4 = *(const float4*)&b2[t0w + ct * 16 + quad * 4];
#pragma unroll
      for (int lt = 0; lt < 4; ++lt) {
        const int nbase = n0 + lt * 16;       // mult of 16 -> wsh uniform
        const int wsh = nbase >> 4;
        size_t rowbase = (((size_t)b * 512) * 64 + (size_t)ih * 16 + wsh) * 64 + iw * 16 + l15;
#pragma unroll
        for (int r = 0; r < 4; ++r) {
          int cout = t0w + ct * 16 + quad * 4 + r;
          out[rowbase + (size_t)cout * 4096] = acc[lt][ct][r] + ((const float*)&bias4)[r];
        }
      }
    }
  }
}

// ---------------------------------------------------------------- launch
extern "C" void kernel_launch(void* const* d_in, const int* in_sizes, int n_in,
                              void* d_out, int out_size, void* d_ws, size_t ws_size,
                              hipStream_t stream) {
  (void)in_sizes; (void)n_in; (void)out_size; (void)ws_size;
  const float* x   = (const float*)d_in[0];
  const float* w1f = (const float*)d_in[1];
  const float* b1  = (const float*)d_in[2];
  const float* w2f = (const float*)d_in[3];
  const float* b2  = (const float*)d_in[4];
  float* out = (float*)d_out;

  char* ws = (char*)d_ws;
  bf16* q   = (bf16*)(ws);
  bf16* k   = (bf16*)(ws + 67108864ull);
  bf16* v   = (bf16*)(ws + 134217728ull);
  bf16* w1p = (bf16*)(ws + 201326592ull);
  bf16* w2p = (bf16*)(ws + 201326592ull + 1572864ull);

  const int LDS_QKV  = (64 * 512 + 8 * 16 * 36) * 2;              //  74,752 B
  const int LDS_ATTN = (256 * 72 + 64 * 264 + 8 * 16 * 264) * 2;  // 138,240 B
  const int LDS_OUT  = 64 * 512 * 2;                              //  65,536 B
  hipFuncSetAttribute(reinterpret_cast<const void*>(gemm_qkv),
                      hipFuncAttributeMaxDynamicSharedMemorySize, LDS_QKV);
  hipFuncSetAttribute(reinterpret_cast<const void*>(attn_win),
                      hipFuncAttributeMaxDynamicSharedMemorySize, LDS_ATTN);
  hipFuncSetAttribute(reinterpret_cast<const void*>(gemm_out),
                      hipFuncAttributeMaxDynamicSharedMemorySize, LDS_OUT);

  hipLaunchKernelGGL(cvt_pack, dim3(512), dim3(256), 0, stream, w1f, w2f, w1p, w2p);
  hipLaunchKernelGGL(gemm_qkv, dim3(1024), dim3(512), LDS_QKV, stream, x, w1p, b1, q, k, v);
  hipLaunchKernelGGL(attn_win, dim3(2048), dim3(512), LDS_ATTN, stream, q, k, v);
  hipLaunchKernelGGL(gemm_out, dim3(1024), dim3(512), LDS_OUT, stream, q, w2p, b2, out);
}

// Round 9
// 615.292 us; speedup vs baseline: 2.1257x; 2.1257x over previous
//
#include <hip/hip_runtime.h>
#include <stdint.h>
#include <stddef.h>
#include <math.h>

// WindowAttention MI355X (gfx950). B=16 C=512 H=W=64 WS=16 HEADS=8 d=64.
// L=256 windows, N=256 positions, attention batches (n,h)=2048 of 256x256,d=64.
//
// R5: de-spill. Evidence: launch_bounds(...,4) pins VGPR=64 (allocator targets
//     8 waves/SIMD tier) and spills accumulators -> GB-scale scratch traffic
//     (R3 full-line stores still showed WRITE 811MB; R4 smaller acc cut WRITE
//     but VGPR stayed 64). R0/R1 with (...,2) allocated 124 VGPR, FETCH 143MB.
//  - both GEMMs: 256-thr blocks, __launch_bounds__(256,2), acc[4][4] (demand
//    ~124 = R1's proven no-spill point), 1-deep weight prefetch.
//  - ONE change vs R1: packed fragment-order weights (w1p/w2p) -> each wave
//    weight load is 1KB over 8 contiguous lines (vs 16 scattered), halving
//    L1/L2 transactions per ks step (R1's latency bottleneck).
//  - attn_win untouched.
//
// Workspace: q[n][h][l][d] 67MB (o overwrites in-place) | k 67MB | v 67MB |
//            w1p bf16 1.5MB | w2p bf16 0.5MB.  Total ~203 MB.

typedef __bf16 bf16;
typedef __attribute__((ext_vector_type(8))) __bf16 bf16x8;
typedef __attribute__((ext_vector_type(4))) __bf16 bf16x4;
typedef __attribute__((ext_vector_type(4))) float f32x4;

#define MFMA16(A, B, C) __builtin_amdgcn_mfma_f32_16x16x32_bf16((A), (B), (C), 0, 0, 0)

__device__ __forceinline__ float fast_exp2(float x) { return __builtin_amdgcn_exp2f(x); }

// XOR-swizzled A-tile element index: rows x 512 cols bf16, unpadded.
// granule (16B) index = (c>>3) ^ (n>>4 & 7) ^ (n & 7): spreads both the
// n-strided staging writes and the b128 frag reads.
__device__ __forceinline__ int aswz(int n, int c) {
  int g = (c >> 3) ^ ((n >> 4) & 7) ^ (n & 7);
  return n * 512 + (g << 3) + (c & 7);
}

// ---------------------------------------------------------------- cvt + pack
// Pack weights into per-wave fragment order:
//   wp[((t*16 + ks)*64 + lane)*8 + e] = wf[t*16 + (lane&15)][ks*32 + (lane>>4)*8 + e]
// so a wave's (tile t, kslice ks) load is one contiguous 1KB block.
// w1: 96 tiles (1536 couts), w2: 32 tiles (512 couts). 1 thread per (t,ks,lane).
__global__ void cvt_pack(const float* __restrict__ w1f, const float* __restrict__ w2f,
                         bf16* __restrict__ w1p, bf16* __restrict__ w2p) {
  int i = blockIdx.x * 256 + threadIdx.x;   // 0..131071
  const float* src;
  bf16* dst;
  if (i < 98304) { src = w1f; dst = w1p; }
  else           { src = w2f; dst = w2p; i -= 98304; }
  int lane = i & 63;
  int ks   = (i >> 6) & 15;
  int t    = i >> 10;
  int cout = t * 16 + (lane & 15);
  int c0   = ks * 32 + (lane >> 4) * 8;
  float4 a = *(const float4*)(src + (size_t)cout * 512 + c0);
  float4 b = *(const float4*)(src + (size_t)cout * 512 + c0 + 4);
  bf16x8 r;
  r[0] = (bf16)a.x; r[1] = (bf16)a.y; r[2] = (bf16)a.z; r[3] = (bf16)a.w;
  r[4] = (bf16)b.x; r[5] = (bf16)b.y; r[6] = (bf16)b.z; r[7] = (bf16)b.w;
  *(bf16x8*)(dst + (size_t)i * 8) = r;
}

// ---------------------------------------------------------------- QKV GEMM
// R1 shape: block = 64 rows x K=512 in swizzled LDS, 4 waves (1x4) x 64 couts,
// 6 cout-chunks of 256. acc[4][4]=64 VGPR, total demand ~124 (no spill at
// launch_bounds(256,2)). Packed weight loads: 4 x contiguous 1KB per ks,
// 1-deep prefetch. Epilogue: per-wave [16][72] transpose -> 128B-line stores.
__global__ void __launch_bounds__(256, 2) gemm_qkv(
    const float* __restrict__ x, const bf16* __restrict__ w1p,
    const float* __restrict__ b1,
    bf16* __restrict__ qo, bf16* __restrict__ ko, bf16* __restrict__ vo) {
  extern __shared__ bf16 Al[];              // 64*512 swizzled + epilogue buf
  bf16* Ep = Al + 64 * 512;                 // 4 waves x [16][72]
  const int tid = threadIdx.x;
  const int bm  = blockIdx.x;               // 0..1023
  const int l   = bm >> 2;
  const int n0  = (bm & 3) << 6;
  const int b   = l >> 4, ih = (l >> 2) & 3, iw = l & 3;
  const int h0  = ih * 16 + (n0 >> 4);      // 4 h-rows of the window
  const int w0  = iw * 16;

  // stage A: 64 n-rows x 512 c, fp32 gather -> bf16 swizzled LDS
  for (int j = 0; j < 32; ++j) {
    int f4  = j * 256 + tid;                // 0..8191
    int c   = f4 >> 4;                      // 16 float4 per channel
    int qq  = f4 & 15;
    int wsh = qq >> 2;                      // 0..3
    int w4  = (qq & 3) << 2;
    float4 xf = *(const float4*)(x + (((b * 512 + c) * 64 + h0 + wsh) * 64 + w0 + w4));
    int nb = wsh * 16 + w4;                 // 0..60
    Al[aswz(nb + 0, c)] = (bf16)xf.x;
    Al[aswz(nb + 1, c)] = (bf16)xf.y;
    Al[aswz(nb + 2, c)] = (bf16)xf.z;
    Al[aswz(nb + 3, c)] = (bf16)xf.w;
  }
  __syncthreads();

  const int wave = tid >> 6, lane = tid & 63;
  const int l15 = lane & 15, quad = lane >> 4;
  bf16* Epw = Ep + wave * 16 * 72;
  const f32x4 fz = {0.f, 0.f, 0.f, 0.f};

  for (int nc = 0; nc < 6; ++nc) {
    const int t0w = nc * 256 + wave * 64;   // 64-aligned -> which/hh wave-uniform
    const int tb  = t0w >> 4;               // base 16-cout tile (4 tiles)
    f32x4 acc[4][4];
#pragma unroll
    for (int a = 0; a < 4; ++a)
#pragma unroll
      for (int c2 = 0; c2 < 4; ++c2) acc[a][c2] = fz;

    bf16x8 bfr[4];
#pragma unroll
    for (int ct = 0; ct < 4; ++ct)
      bfr[ct] = *(const bf16x8*)&w1p[((size_t)((tb + ct) * 16 + 0) * 64 + lane) * 8];
#pragma unroll
    for (int ks = 0; ks < 16; ++ks) {
      bf16x8 bnx[4];
      if (ks < 15) {
#pragma unroll
        for (int ct = 0; ct < 4; ++ct)
          bnx[ct] = *(const bf16x8*)&w1p[((size_t)((tb + ct) * 16 + ks + 1) * 64 + lane) * 8];
      }
      bf16x8 af[4];
#pragma unroll
      for (int lt = 0; lt < 4; ++lt)
        af[lt] = *(const bf16x8*)&Al[aswz(lt * 16 + l15, ks * 32 + quad * 8)];
#pragma unroll
      for (int lt = 0; lt < 4; ++lt)
#pragma unroll
        for (int ct = 0; ct < 4; ++ct)
          acc[lt][ct] = MFMA16(af[lt], bfr[ct], acc[lt][ct]);
#pragma unroll
      for (int ct = 0; ct < 4; ++ct) bfr[ct] = bnx[ct];
    }

    // epilogue: per-wave [16][72] transpose -> 128B contiguous bf16x8 stores
    const int which = t0w >> 9;
    const int hh = (t0w & 511) >> 6;
    bf16* dst = (which == 0) ? qo : (which == 1) ? ko : vo;
    const float scale = (which == 0) ? 0.125f : 1.0f;
    float bias[4];
#pragma unroll
    for (int ct = 0; ct < 4; ++ct) bias[ct] = b1[t0w + ct * 16 + l15];

#pragma unroll
    for (int lt = 0; lt < 4; ++lt) {
#pragma unroll
      for (int ct = 0; ct < 4; ++ct)
#pragma unroll
        for (int r = 0; r < 4; ++r)
          Epw[(quad * 4 + r) * 72 + ct * 16 + l15] =
              (bf16)((acc[lt][ct][r] + bias[ct]) * scale);
      const int rr = lane >> 3, ch8 = (lane & 7) * 8;
#pragma unroll
      for (int half = 0; half < 2; ++half) {
        int row = half * 8 + rr;
        bf16x8 vv = *(const bf16x8*)&Epw[row * 72 + ch8];
        int n = n0 + lt * 16 + row;
        *(bf16x8*)&dst[((size_t)(n * 8 + hh) * 256 + l) * 64 + ch8] = vv;
      }
    }
  }
}

// ---------------------------------------------------------------- attention
// One block per (n,h). K LDS [256][72], V^T LDS [64][264], per-wave P [16][264].
// Output overwrites q in-place; writes via per-wave transpose -> 128B chunks.
__global__ void __launch_bounds__(512, 2) attn_win(
    bf16* __restrict__ qio, const bf16* __restrict__ kg, const bf16* __restrict__ vg) {
  extern __shared__ bf16 sm[];
  bf16* Kl = sm;
  bf16* Vt = sm + 256 * 72;
  bf16* Pl = Vt + 64 * 264;
  const int tid = threadIdx.x;
  const int bb = blockIdx.x;
  const int n = bb >> 3, h = bb & 7;
  const size_t base = (size_t)(n * 8 + h) * 16384;
  const bf16* Kg = kg + base;
  const bf16* Vg = vg + base;
  bf16* Qg = qio + base;

  for (int j = 0; j < 4; ++j) {
    int cc = j * 512 + tid;
    int m = cc >> 3, dc = cc & 7;
    bf16x8 t = *(const bf16x8*)(Kg + m * 64 + dc * 8);
    *(bf16x8*)&Kl[m * 72 + dc * 8] = t;
  }
  for (int j = 0; j < 4; ++j) {
    int cc = j * 512 + tid;
    int dc = cc >> 8, m = cc & 255;
    bf16x8 t = *(const bf16x8*)(Vg + m * 64 + dc * 8);
#pragma unroll
    for (int s = 0; s < 8; ++s) Vt[(dc * 8 + s) * 264 + m] = t[s];
  }

  const int wave = tid >> 6, lane = tid & 63;
  const int l15 = lane & 15, quad = lane >> 4;
  const int lb = wave * 32;
  bf16* Pw = Pl + wave * 16 * 264;

  bf16x8 qf[2][2];
#pragma unroll
  for (int lt = 0; lt < 2; ++lt)
#pragma unroll
    for (int ks = 0; ks < 2; ++ks)
      qf[lt][ks] = *(const bf16x8*)(Qg + (lb + lt * 16 + l15) * 64 + ks * 32 + quad * 8);

  __syncthreads();

  const f32x4 fz = {0.f, 0.f, 0.f, 0.f};
  const float LOG2E = 1.44269504088896340736f;
  for (int lt = 0; lt < 2; ++lt) {
    f32x4 s[16];
#pragma unroll
    for (int mt = 0; mt < 16; ++mt) s[mt] = fz;
#pragma unroll
    for (int mt = 0; mt < 16; ++mt)
#pragma unroll
      for (int ks = 0; ks < 2; ++ks) {
        bf16x8 kf = *(const bf16x8*)&Kl[(mt * 16 + l15) * 72 + ks * 32 + quad * 8];
        s[mt] = MFMA16(qf[lt][ks], kf, s[mt]);
      }
    float rmax[4], rsum[4];
#pragma unroll
    for (int r = 0; r < 4; ++r) {
      float mx = s[0][r];
#pragma unroll
      for (int mt = 1; mt < 16; ++mt) mx = fmaxf(mx, s[mt][r]);
#pragma unroll
      for (int xo = 1; xo < 16; xo <<= 1) mx = fmaxf(mx, __shfl_xor(mx, xo, 16));
      rmax[r] = mx;
      rsum[r] = 0.f;
    }
#pragma unroll
    for (int mt = 0; mt < 16; ++mt) {
#pragma unroll
      for (int r = 0; r < 4; ++r) {
        float p = fast_exp2((s[mt][r] - rmax[r]) * LOG2E);
        bf16 pb = (bf16)p;
        rsum[r] += (float)pb;
        Pw[(quad * 4 + r) * 264 + mt * 16 + l15] = pb;
      }
    }
#pragma unroll
    for (int r = 0; r < 4; ++r)
#pragma unroll
      for (int xo = 1; xo < 16; xo <<= 1) rsum[r] += __shfl_xor(rsum[r], xo, 16);

    bf16x8 pf[8];
#pragma unroll
    for (int mk = 0; mk < 8; ++mk)
      pf[mk] = *(const bf16x8*)&Pw[l15 * 264 + mk * 32 + quad * 8];
    f32x4 of[4];
#pragma unroll
    for (int dt = 0; dt < 4; ++dt) of[dt] = fz;
#pragma unroll
    for (int dt = 0; dt < 4; ++dt)
#pragma unroll
      for (int mk = 0; mk < 8; ++mk) {
        bf16x8 vf = *(const bf16x8*)&Vt[(dt * 16 + l15) * 264 + mk * 32 + quad * 8];
        of[dt] = MFMA16(pf[mk], vf, of[dt]);
      }
    float inv[4];
#pragma unroll
    for (int r = 0; r < 4; ++r) inv[r] = 1.0f / rsum[r];

    // o-write: per-wave transpose (reuse Pw) -> 128B contiguous bf16x8 stores
    bf16* Ew = Pw;  // [16][72] region
#pragma unroll
    for (int dt = 0; dt < 4; ++dt)
#pragma unroll
      for (int r = 0; r < 4; ++r)
        Ew[(quad * 4 + r) * 72 + dt * 16 + l15] = (bf16)(of[dt][r] * inv[r]);
    const int rr = lane >> 3, ch8 = (lane & 7) * 8;
#pragma unroll
    for (int half = 0; half < 2; ++half) {
      int row = half * 8 + rr;
      bf16x8 vv = *(const bf16x8*)&Ew[row * 72 + ch8];
      *(bf16x8*)(Qg + (lb + lt * 16 + row) * 64 + ch8) = vv;
    }
  }
}

// ---------------------------------------------------------------- out proj
// Swapped MFMA operands: D = W2 x O^T, C-layout row=cout col=n, so stores are
// 64B-contiguous fp32 along w. R1 shape: 256-thr, 4 waves x 64 couts, 2 chunks,
// acc[4][4], packed w2p with 1-deep prefetch.
__global__ void __launch_bounds__(256, 2) gemm_out(
    const bf16* __restrict__ og, const bf16* __restrict__ w2p,
    const float* __restrict__ b2, float* __restrict__ out) {
  extern __shared__ bf16 Al[];  // 64*512 swizzled
  const int tid = threadIdx.x;
  const int bm = blockIdx.x;    // 0..1023
  const int l = bm >> 2;
  const int n0 = (bm & 3) << 6;
  const int b = l >> 4, ih = (l >> 2) & 3, iw = l & 3;

  for (int j = 0; j < 16; ++j) {  // o[n][h][l][d] gather -> swizzled LDS rows
    int cc = j * 256 + tid;       // 0..4095
    int nl = cc >> 6;             // 0..63
    int ch = cc & 63;
    int hh = ch >> 3, d8 = (ch & 7) * 8;
    bf16x8 t = *(const bf16x8*)(og + ((size_t)((n0 + nl) * 8 + hh) * 256 + l) * 64 + d8);
    *(bf16x8*)&Al[aswz(nl, ch * 8)] = t;
  }
  __syncthreads();

  const int wave = tid >> 6, lane = tid & 63;
  const int l15 = lane & 15, quad = lane >> 4;
  const f32x4 fz = {0.f, 0.f, 0.f, 0.f};

  for (int nc = 0; nc < 2; ++nc) {
    const int t0w = nc * 256 + wave * 64;
    const int tb  = t0w >> 4;
    f32x4 acc[4][4];
#pragma unroll
    for (int a = 0; a < 4; ++a)
#pragma unroll
      for (int c2 = 0; c2 < 4; ++c2) acc[a][c2] = fz;

    bf16x8 bfr[4];
#pragma unroll
    for (int ct = 0; ct < 4; ++ct)
      bfr[ct] = *(const bf16x8*)&w2p[((size_t)((tb + ct) * 16 + 0) * 64 + lane) * 8];
#pragma unroll
    for (int ks = 0; ks < 16; ++ks) {
      bf16x8 bnx[4];
      if (ks < 15) {
#pragma unroll
        for (int ct = 0; ct < 4; ++ct)
          bnx[ct] = *(const bf16x8*)&w2p[((size_t)((tb + ct) * 16 + ks + 1) * 64 + lane) * 8];
      }
      bf16x8 af[4];
#pragma unroll
      for (int lt = 0; lt < 4; ++lt)
        af[lt] = *(const bf16x8*)&Al[aswz(lt * 16 + l15, ks * 32 + quad * 8)];
#pragma unroll
      for (int lt = 0; lt < 4; ++lt)
#pragma unroll
        for (int ct = 0; ct < 4; ++ct)
          acc[lt][ct] = MFMA16(bfr[ct], af[lt], acc[lt][ct]);  // swapped: rows=cout
#pragma unroll
      for (int ct = 0; ct < 4; ++ct) bfr[ct] = bnx[ct];
    }

#pragma unroll
    for (int ct = 0; ct < 4; ++ct) {
      float4 bias4 = *(const float4*)&b2[t0w + ct * 16 + quad * 4];
#pragma unroll
      for (int lt = 0; lt < 4; ++lt) {
        const int nbase = n0 + lt * 16;       // mult of 16 -> wsh uniform
        const int wsh = nbase >> 4;
        size_t rowbase = (((size_t)b * 512) * 64 + (size_t)ih * 16 + wsh) * 64 + iw * 16 + l15;
#pragma unroll
        for (int r = 0; r < 4; ++r) {
          int cout = t0w + ct * 16 + quad * 4 + r;
          out[rowbase + (size_t)cout * 4096] = acc[lt][ct][r] + ((const float*)&bias4)[r];
        }
      }
    }
  }
}

// ---------------------------------------------------------------- launch
extern "C" void kernel_launch(void* const* d_in, const int* in_sizes, int n_in,
                              void* d_out, int out_size, void* d_ws, size_t ws_size,
                              hipStream_t stream) {
  (void)in_sizes; (void)n_in; (void)out_size; (void)ws_size;
  const float* x   = (const float*)d_in[0];
  const float* w1f = (const float*)d_in[1];
  const float* b1  = (const float*)d_in[2];
  const float* w2f = (const float*)d_in[3];
  const float* b2  = (const float*)d_in[4];
  float* out = (float*)d_out;

  char* ws = (char*)d_ws;
  bf16* q   = (bf16*)(ws);
  bf16* k   = (bf16*)(ws + 67108864ull);
  bf16* v   = (bf16*)(ws + 134217728ull);
  bf16* w1p = (bf16*)(ws + 201326592ull);
  bf16* w2p = (bf16*)(ws + 201326592ull + 1572864ull);

  const int LDS_QKV  = (64 * 512 + 4 * 16 * 72) * 2;              //  74,752 B
  const int LDS_ATTN = (256 * 72 + 64 * 264 + 8 * 16 * 264) * 2;  // 138,240 B
  const int LDS_OUT  = 64 * 512 * 2;                              //  65,536 B
  hipFuncSetAttribute(reinterpret_cast<const void*>(gemm_qkv),
                      hipFuncAttributeMaxDynamicSharedMemorySize, LDS_QKV);
  hipFuncSetAttribute(reinterpret_cast<const void*>(attn_win),
                      hipFuncAttributeMaxDynamicSharedMemorySize, LDS_ATTN);
  hipFuncSetAttribute(reinterpret_cast<const void*>(gemm_out),
                      hipFuncAttributeMaxDynamicSharedMemorySize, LDS_OUT);

  hipLaunchKernelGGL(cvt_pack, dim3(512), dim3(256), 0, stream, w1f, w2f, w1p, w2p);
  hipLaunchKernelGGL(gemm_qkv, dim3(1024), dim3(256), LDS_QKV, stream, x, w1p, b1, q, k, v);
  hipLaunchKernelGGL(attn_win, dim3(2048), dim3(512), LDS_ATTN, stream, q, k, v);
  hipLaunchKernelGGL(gemm_out, dim3(1024), dim3(256), LDS_OUT, stream, q, w2p, b2, out);
}